// Round 14
// baseline (96.285 us; speedup 1.0000x reference)
//
#include <hip/hip_runtime.h>
#include <stdint.h>

#define NB 64
#define NN 1024
#define CDIM 512
#define KK 64

typedef __attribute__((ext_vector_type(4))) float f32x4;
typedef __attribute__((ext_vector_type(8))) short short8;
typedef __attribute__((ext_vector_type(4))) unsigned short u16x4;

__device__ __forceinline__ unsigned short f2bf(float f) {
  unsigned int u = __float_as_uint(f);
  return (unsigned short)((u + 0x7fffu + ((u >> 16) & 1u)) >> 16);
}

// ---------------- K0: centers fp32 -> bf16 ----------------
__global__ __launch_bounds__(256) void k0_cvt(const float* __restrict__ cc,
                                              unsigned short* __restrict__ ccb) {
  int i = blockIdx.x * 256 + threadIdx.x;   // grid sized exactly KK*CDIM/256
  ccb[i] = f2bf(cc[i]);
}

// ---- K_FUSED: logits + softmax + agg, single pass over x ----
// grid: (4 n-quarters, 64 b) = 256 blocks = 1/CU, 256 thr = 4 waves.
// Block owns 256 n; 4 chunks of 64 n. Per chunk:
//  stage (linear 1KB loads) -> x_sm bf16 [64n][512c] XOR((n&7)<<4 ush)
//  MFMA1: wave w computes logits for its n-rows [16w,+16) (frag reads from
//         x_sm, ccb frags L1-hot); af frags pair-shuffled into xT_sm
//         [512c][32 n-pair u32, stride 36, XOR((c&7)<<2)]
//  softmax in-register (D1: lane=(lr,lg) holds [n=lg*4+j][k=tk*16+lr])
//  a -> a_sm [64k][stride 36 u32]; asum accumulated in registers
//  MFMA2: wave w owns k-tile [16w,+16) x all 512 c: acc2[32] f32x4 (128 VGPR)
// Epilogue: acc2 -> LDS(fbuf) -> LINEAR f32x4 stores to pagg[b][q][64][512];
//           a_sum atomics.
__global__ __launch_bounds__(256, 1) void k_fused(const float* __restrict__ x,
    const unsigned short* __restrict__ ccb, float* __restrict__ a_sum,
    float* __restrict__ pagg) {
  const int q = blockIdx.x;
  const int b = blockIdx.y;
  const int tid = threadIdx.x;
  const int w = tid >> 6;
  const int l = tid & 63;
  const int lr = l & 15;
  const int lg = l >> 4;
  const int codd = l & 1;

  __shared__ unsigned short x_sm[64 * 512];   // 64 KiB
  __shared__ unsigned int xT_sm[512 * 36];    // 72 KiB
  __shared__ unsigned int a_sm[64 * 36];      // 9 KiB

  f32x4 acc2[32];
  #pragma unroll
  for (int i = 0; i < 32; ++i) acc2[i] = (f32x4){0.f, 0.f, 0.f, 0.f};
  float asr0 = 0.f, asr1 = 0.f, asr2 = 0.f, asr3 = 0.f;

  const unsigned short* cb = ccb + lr * CDIM + (lg << 3);
  const int nrow = (w << 4) + lr;             // lane's MFMA1 A-row in chunk
  const int xsw = (nrow & 7) << 4;

  for (int ch = 0; ch < 4; ++ch) {
    // ---- stage: wave w stages chunk rows [16w,16w+16), linear 1KB loads ----
    {
      const float* xrow =
          x + ((size_t)b * NN + (q << 8) + (ch << 6) + (w << 4)) * CDIM;
      #pragma unroll
      for (int r = 0; r < 16; ++r) {
        const int n = (w << 4) + r;
        const float* rp = xrow + (size_t)r * CDIM;
        f32x4 va = *(const f32x4*)(rp + (l << 2));
        f32x4 vb = *(const f32x4*)(rp + 256 + (l << 2));
        u16x4 pa, pb;
        pa[0] = f2bf(va[0]); pa[1] = f2bf(va[1]);
        pa[2] = f2bf(va[2]); pa[3] = f2bf(va[3]);
        pb[0] = f2bf(vb[0]); pb[1] = f2bf(vb[1]);
        pb[2] = f2bf(vb[2]); pb[3] = f2bf(vb[3]);
        const int sw = (n & 7) << 4;
        *(u16x4*)&x_sm[(n << 9) + (((l << 2)) ^ sw)] = pa;
        *(u16x4*)&x_sm[(n << 9) + (((l << 2) + 256) ^ sw)] = pb;
      }
    }
    __syncthreads();

    // ---- MFMA1 + xT build ----
    f32x4 acc1[4];
    #pragma unroll
    for (int i = 0; i < 4; ++i) acc1[i] = (f32x4){0.f, 0.f, 0.f, 0.f};
    #pragma unroll 4
    for (int s = 0; s < 16; ++s) {
      const int cs = s << 5;
      short8 af = *(const short8*)&x_sm[(nrow << 9) + ((cs + (lg << 3)) ^ xsw)];
      short8 b0 = *(const short8*)(cb + cs);
      short8 b1 = *(const short8*)(cb + 16 * CDIM + cs);
      short8 b2 = *(const short8*)(cb + 32 * CDIM + cs);
      short8 b3 = *(const short8*)(cb + 48 * CDIM + cs);
      acc1[0] = __builtin_amdgcn_mfma_f32_16x16x32_bf16(af, b0, acc1[0], 0, 0, 0);
      acc1[1] = __builtin_amdgcn_mfma_f32_16x16x32_bf16(af, b1, acc1[1], 0, 0, 0);
      acc1[2] = __builtin_amdgcn_mfma_f32_16x16x32_bf16(af, b2, acc1[2], 0, 0, 0);
      acc1[3] = __builtin_amdgcn_mfma_f32_16x16x32_bf16(af, b3, acc1[3], 0, 0, 0);
      // xT pack: lane-pair (n, n^1); u32 = {bf16 n_even, bf16 n_odd} at col c
      #pragma unroll
      for (int qq = 0; qq < 4; ++qq) {
        unsigned int own = ((const unsigned int*)&af)[qq];
        unsigned int oth = (unsigned int)__shfl_xor((int)own, 1);
        unsigned int v = codd ? ((oth >> 16) | (own & 0xffff0000u))
                              : ((own & 0xffffu) | (oth << 16));
        const int c = cs + (lg << 3) + (qq << 1) + codd;
        xT_sm[c * 36 + (((w << 3) + (lr >> 1)) ^ ((c & 7) << 2))] = v;
      }
    }

    // ---- softmax (in-register) + a_sm pack + asum accumulate ----
    #pragma unroll
    for (int j = 0; j < 4; ++j) {
      float m = fmaxf(fmaxf(acc1[0][j], acc1[1][j]),
                      fmaxf(acc1[2][j], acc1[3][j]));
      m = fmaxf(m, __shfl_xor(m, 1));
      m = fmaxf(m, __shfl_xor(m, 2));
      m = fmaxf(m, __shfl_xor(m, 4));
      m = fmaxf(m, __shfl_xor(m, 8));
      float e0 = __expf(acc1[0][j] - m);
      float e1 = __expf(acc1[1][j] - m);
      float e2 = __expf(acc1[2][j] - m);
      float e3 = __expf(acc1[3][j] - m);
      float s = e0 + e1 + e2 + e3;
      s += __shfl_xor(s, 1); s += __shfl_xor(s, 2);
      s += __shfl_xor(s, 4); s += __shfl_xor(s, 8);
      float inv = 1.0f / s;
      acc1[0][j] = e0 * inv; acc1[1][j] = e1 * inv;
      acc1[2][j] = e2 * inv; acc1[3][j] = e3 * inv;
      asr0 += acc1[0][j]; asr1 += acc1[1][j];
      asr2 += acc1[2][j]; asr3 += acc1[3][j];
    }
    #pragma unroll
    for (int tk = 0; tk < 4; ++tk) {
      #pragma unroll
      for (int jp = 0; jp < 2; ++jp) {
        unsigned int v = (unsigned int)f2bf(acc1[tk][2 * jp]) |
                         ((unsigned int)f2bf(acc1[tk][2 * jp + 1]) << 16);
        a_sm[((tk << 4) + lr) * 36 + (w << 3) + (lg << 1) + jp] = v;
      }
    }
    __syncthreads();

    // ---- MFMA2: agg[k-tile 16w..+16][all c] += a^T x over this chunk ----
    #pragma unroll
    for (int ns = 0; ns < 2; ++ns) {
      short8 a2 = *(const short8*)&a_sm[((w << 4) + lr) * 36 + (ns << 4) + (lg << 2)];
      #pragma unroll
      for (int ct = 0; ct < 32; ++ct) {
        const int c = (ct << 4) + lr;
        short8 b2 = *(const short8*)&xT_sm[c * 36 +
            (((ns << 4) + (lg << 2)) ^ ((c & 7) << 2))];
        acc2[ct] = __builtin_amdgcn_mfma_f32_16x16x32_bf16(a2, b2, acc2[ct], 0, 0, 0);
      }
    }
    __syncthreads();
  }

  // ---- a_sum atomics (reduce over lg groups first) ----
  {
    float s0 = asr0, s1 = asr1, s2 = asr2, s3 = asr3;
    s0 += __shfl_xor(s0, 16); s0 += __shfl_xor(s0, 32);
    s1 += __shfl_xor(s1, 16); s1 += __shfl_xor(s1, 32);
    s2 += __shfl_xor(s2, 16); s2 += __shfl_xor(s2, 32);
    s3 += __shfl_xor(s3, 16); s3 += __shfl_xor(s3, 32);
    if (lg == 0) {
      atomicAdd(&a_sum[(b << 6) + lr], s0);
      atomicAdd(&a_sum[(b << 6) + 16 + lr], s1);
      atomicAdd(&a_sum[(b << 6) + 32 + lr], s2);
      atomicAdd(&a_sum[(b << 6) + 48 + lr], s3);
    }
  }

  // ---- partial agg -> LDS -> linear stores (2 passes of 256 c) ----
  float* fbuf = (float*)x_sm;   // reuse: [64 k][256 c] f32 = 64 KiB
  float* pg = pagg + (((size_t)((b << 2) + q)) << 15);
  #pragma unroll
  for (int pass = 0; pass < 2; ++pass) {
    __syncthreads();
    #pragma unroll
    for (int ct = 0; ct < 16; ++ct) {
      #pragma unroll
      for (int j = 0; j < 4; ++j) {
        fbuf[((w << 4) + (lg << 2) + j) * 256 + (ct << 4) + lr] =
            acc2[pass * 16 + ct][j];
      }
    }
    __syncthreads();
    #pragma unroll
    for (int i = 0; i < 16; ++i) {
      const int f = (i << 8) + tid;        // f32x4 id in [0,4096)
      f32x4 v = ((const f32x4*)fbuf)[f];
      const int k = f >> 6;
      const int c4 = (f & 63) << 2;
      *(f32x4*)(pg + (k << 9) + (pass << 8) + c4) = v;
    }
  }
}

// ---- K_FINAL: vlad = sum_q pagg - a_sum*cc; out write; sumsq atomics ----
// grid (16 slices, 64 b), 256 thr; slice = 2048 consecutive out floats.
__global__ __launch_bounds__(256) void k_final(const float* __restrict__ pagg,
    const float* __restrict__ a_sum, const float* __restrict__ cc,
    float* __restrict__ out, float* __restrict__ sumsq) {
  const int b = blockIdx.y;
  const int sl = blockIdx.x;
  const int tid = threadIdx.x;
  __shared__ float red[4];
  const float* p0 = pagg + (((size_t)(b << 2)) << 15) + (sl << 11);
  float lsum = 0.f;
  #pragma unroll
  for (int i = 0; i < 2; ++i) {
    const int f = (i << 10) + (tid << 2);
    f32x4 v0 = *(const f32x4*)(p0 + f);
    f32x4 v1 = *(const f32x4*)(p0 + (1 << 15) + f);
    f32x4 v2 = *(const f32x4*)(p0 + (2 << 15) + f);
    f32x4 v3 = *(const f32x4*)(p0 + (3 << 15) + f);
    const int k = ((sl << 11) + f) >> 9;
    const float as = a_sum[(b << 6) + k];
    f32x4 cv = *(const f32x4*)(cc + (sl << 11) + f);
    f32x4 r;
    r[0] = v0[0] + v1[0] + v2[0] + v3[0] - as * cv[0];
    r[1] = v0[1] + v1[1] + v2[1] + v3[1] - as * cv[1];
    r[2] = v0[2] + v1[2] + v2[2] + v3[2] - as * cv[2];
    r[3] = v0[3] + v1[3] + v2[3] + v3[3] - as * cv[3];
    *(f32x4*)(out + ((size_t)b << 15) + (sl << 11) + f) = r;
    lsum += r[0] * r[0] + r[1] * r[1] + r[2] * r[2] + r[3] * r[3];
  }
  lsum += __shfl_xor(lsum, 1);  lsum += __shfl_xor(lsum, 2);
  lsum += __shfl_xor(lsum, 4);  lsum += __shfl_xor(lsum, 8);
  lsum += __shfl_xor(lsum, 16); lsum += __shfl_xor(lsum, 32);
  if ((tid & 63) == 0) red[tid >> 6] = lsum;
  __syncthreads();
  if (tid == 0) atomicAdd(&sumsq[b], red[0] + red[1] + red[2] + red[3]);
}

// ---------------- K3: l2 normalize per batch ----------------
__global__ __launch_bounds__(256) void k3_norm(float* __restrict__ out,
                                               const float* __restrict__ sumsq) {
  int idx = blockIdx.x * 256 + threadIdx.x;   // grid exact: 2048*256 = 2M/4
  int b = idx >> 13;                          // 8192 float4 per batch
  float s = sumsq[b];
  float scale = 1.0f / sqrtf(fmaxf(s, 1e-12f));
  f32x4* io = (f32x4*)out;
  f32x4 v = io[idx];
  v[0] *= scale; v[1] *= scale; v[2] *= scale; v[3] *= scale;
  io[idx] = v;
}

extern "C" void kernel_launch(void* const* d_in, const int* in_sizes, int n_in,
                              void* d_out, int out_size, void* d_ws, size_t ws_size,
                              hipStream_t stream) {
  const float* x  = (const float*)d_in[0];
  const float* cc = (const float*)d_in[1];
  float* out = (float*)d_out;
  char* ws = (char*)d_ws;
  // ws: [ccb 64KiB @0][a_sum 16KiB @64K][sumsq 256B @80K][pagg 32MiB @1MiB]
  unsigned short* ccb = (unsigned short*)ws;
  float* a_sum = (float*)(ws + (64u << 10));
  float* sumsq = (float*)(ws + (80u << 10));
  float* pagg  = (float*)(ws + (1u << 20));

  (void)hipMemsetAsync(a_sum, 0, NB * KK * 4 + NB * 4, stream);
  k0_cvt<<<dim3((KK * CDIM) / 256), 256, 0, stream>>>(cc, ccb);
  k_fused<<<dim3(4, NB), 256, 0, stream>>>(x, ccb, a_sum, pagg);
  k_final<<<dim3(16, NB), 256, 0, stream>>>(pagg, a_sum, cc, out, sumsq);
  k3_norm<<<dim3(2048), 256, 0, stream>>>(out, sumsq);
}